// Round 6
// baseline (430.575 us; speedup 1.0000x reference)
//
#include <hip/hip_runtime.h>

#define N_NODES  100000
#define N_EDGES  1600000
#define NF       128
#define N_GRAPHS 100
#define NBKT     196         // ceil(100000 / 512) coarse buckets
#define BKT_SHIFT 9
#define CAP      12288       // bucket capacity; mean 8192, ~45 sigma margin (fixed input)
#define EPB      4096        // edges per block in bscatter
#define EB_GRID  391         // ceil(1600000 / 4096)

typedef __attribute__((ext_vector_type(8))) short bf16x8;
typedef __attribute__((ext_vector_type(4))) float f32x4;
typedef unsigned int uint32;

// ---------------------------------------------------------------- bf16 helpers (RNE)
__device__ __forceinline__ unsigned short f2bf(float f) {
    union { float f; uint32 u; } x; x.f = f;
    return (unsigned short)((x.u + 0x7fffu + ((x.u >> 16) & 1u)) >> 16);
}
__device__ __forceinline__ uint32 pack2bf(float a, float b) {
    union { float f; uint32 u; } x, y; x.f = a; y.f = b;
    uint32 lo = (x.u + 0x7fffu + ((x.u >> 16) & 1u)) >> 16;
    uint32 hi = (y.u + 0x7fffu + ((y.u >> 16) & 1u)) & 0xffff0000u;
    return lo | hi;
}

// ---------------------------------------------------------------- prep: x->bf16, W1..4->bf16, zero cursors+sums
__global__ __launch_bounds__(256) void prep(const float4* __restrict__ x,
                                            const float4* __restrict__ w1,
                                            const float4* __restrict__ w2,
                                            const float4* __restrict__ w3,
                                            const float4* __restrict__ w4,
                                            uint4* __restrict__ xb, uint4* __restrict__ wb,
                                            int* __restrict__ cur, float* __restrict__ sums) {
    int bid = blockIdx.x, t = threadIdx.x;
    if (bid < 6250) {                               // x: 1.6M uint4 outputs exactly
        int i = bid * 256 + t;
        float4 a = x[i * 2], b = x[i * 2 + 1];
        uint4 o;
        o.x = pack2bf(a.x, a.y); o.y = pack2bf(a.z, a.w);
        o.z = pack2bf(b.x, b.y); o.w = pack2bf(b.z, b.w);
        xb[i] = o;
    } else if (bid < 6282) {                        // weights: 8192 uint4
        int i = (bid - 6250) * 256 + t;
        int wi = i >> 11, li = i & 2047;
        const float4* s = (wi == 0) ? w1 : (wi == 1) ? w2 : (wi == 2) ? w3 : w4;
        float4 a = s[li * 2], b = s[li * 2 + 1];
        uint4 o;
        o.x = pack2bf(a.x, a.y); o.y = pack2bf(a.z, a.w);
        o.z = pack2bf(b.x, b.y); o.w = pack2bf(b.z, b.w);
        wb[i] = o;
    } else {                                        // zero cur[196] + sums[12800]
        int idx = (bid - 6282) * 256 + t;           // 16 blocks -> 4096 threads
        for (int i = idx; i < N_GRAPHS * NF; i += 4096) sums[i] = 0.f;
        if (idx < NBKT) cur[idx] = 0;
    }
}

// ---------------------------------------------------------------- CSR A: scatter edges into fixed-cap coarse buckets
// packed entry: (dstLocal<<17) | src   (src < 131072)
__global__ __launch_bounds__(256) void bscatter(const int* __restrict__ src,
                                                const int* __restrict__ dst,
                                                int* __restrict__ cur,
                                                uint32* __restrict__ ebuf) {
    __shared__ int lh[NBKT], lbase[NBKT];
    int t = threadIdx.x;
    if (t < NBKT) lh[t] = 0;
    __syncthreads();
    int e0 = blockIdx.x * EPB;
    int d[16];
    #pragma unroll
    for (int i = 0; i < 16; ++i) {
        int e = e0 + i * 256 + t;
        d[i] = -1;
        if (e < N_EDGES) { d[i] = dst[e]; atomicAdd(&lh[d[i] >> BKT_SHIFT], 1); }
    }
    __syncthreads();
    if (t < NBKT) { lbase[t] = t * CAP + atomicAdd(&cur[t], lh[t]); lh[t] = 0; }
    __syncthreads();
    #pragma unroll
    for (int i = 0; i < 16; ++i) {
        int e = e0 + i * 256 + t;
        if (e < N_EDGES) {
            int b = d[i] >> BKT_SHIFT;
            int off = atomicAdd(&lh[b], 1);
            ebuf[lbase[b] + off] = ((uint32)(d[i] & 511) << 17) | (uint32)src[e];
        }
    }
}

// ---------------------------------------------------------------- CSR B: per-bucket fine counting sort (512 nodes)
__global__ __launch_bounds__(512) void bfine(const uint32* __restrict__ ebuf,
                                             const int* __restrict__ cur,
                                             int* __restrict__ rowptr,
                                             int* __restrict__ rowend,
                                             int* __restrict__ csr) {
    __shared__ int deg[512], off[512];
    int t = threadIdx.x;
    int bkt = blockIdx.x;
    int beg = bkt * CAP;
    int end = beg + cur[bkt];
    deg[t] = 0;
    __syncthreads();
    for (int e = beg + t; e < end; e += 512)
        atomicAdd(&deg[ebuf[e] >> 17], 1);
    __syncthreads();
    int d = deg[t];
    off[t] = d;
    __syncthreads();
    for (int o = 1; o < 512; o <<= 1) {             // Hillis-Steele inclusive
        int x = (t >= o) ? off[t - o] : 0;
        __syncthreads();
        off[t] += x;
        __syncthreads();
    }
    int ex = off[t] - d;                            // exclusive
    int node = (bkt << BKT_SHIFT) + t;
    if (node < N_NODES) { rowptr[node] = beg + ex; rowend[node] = beg + ex + d; }
    __syncthreads();
    off[t] = ex;                                    // becomes write cursor
    __syncthreads();
    for (int e = beg + t; e < end; e += 512) {
        uint32 u = ebuf[e];
        int pos = atomicAdd(&off[u >> 17], 1);
        csr[beg + pos] = (int)(u & 0x1FFFFu);
    }
}

// ---------------------------------------------------------------- bf16 gather: out[n] = x[n] + sum x[csr[e]]
__global__ __launch_bounds__(256) void gather_agg_bf16(const uint4* __restrict__ x,
                                                       const int* __restrict__ rowptr,
                                                       const int* __restrict__ rowend,
                                                       const int* __restrict__ csr,
                                                       uint4* __restrict__ out) {
    int idx = blockIdx.x * 256 + threadIdx.x;
    int node = idx >> 4, c = idx & 15;
    int beg = rowptr[node], end = rowend[node];

    float acc[8];
    {
        uint4 v = x[node * 16 + c];
        uint32 u[4] = {v.x, v.y, v.z, v.w};
        #pragma unroll
        for (int i = 0; i < 4; ++i) {
            union { uint32 b; float f; } lo, hi;
            lo.b = u[i] << 16; hi.b = u[i] & 0xffff0000u;
            acc[2 * i] = lo.f; acc[2 * i + 1] = hi.f;
        }
    }
    for (int e = beg; e < end; ++e) {
        int s = csr[e];
        uint4 v = x[s * 16 + c];
        uint32 u[4] = {v.x, v.y, v.z, v.w};
        #pragma unroll
        for (int i = 0; i < 4; ++i) {
            union { uint32 b; float f; } lo, hi;
            lo.b = u[i] << 16; hi.b = u[i] & 0xffff0000u;
            acc[2 * i] += lo.f; acc[2 * i + 1] += hi.f;
        }
    }
    uint4 o;
    o.x = pack2bf(acc[0], acc[1]); o.y = pack2bf(acc[2], acc[3]);
    o.z = pack2bf(acc[4], acc[5]); o.w = pack2bf(acc[6], acc[7]);
    out[node * 16 + c] = o;
}

// ---------------------------------------------------------------- fused MLP: C = relu(relu(A Wa^T + ba) Wb^T + bb)
// A-frags + W-frags straight from global (A line-coalesced, each elem read once;
// W is 32KB L1/L2-resident). Only mid lives in LDS (35KB -> 4 blocks/CU, 1 barrier).
// Each wave's pass-1 C rows == its pass-2 A rows, so one barrier is even conservative.
template <bool F32OUT>
__global__ __launch_bounds__(256, 4) void mlp_mfma(const unsigned short* __restrict__ A,
                                                   const unsigned short* __restrict__ Wa,
                                                   const float* __restrict__ ba,
                                                   const unsigned short* __restrict__ Wb,
                                                   const float* __restrict__ bb,
                                                   void* __restrict__ Cout, int M) {
    __shared__ unsigned short Mid[128 * 136];       // +8 pad: quad reads 2-way alias = free
    int tid  = threadIdx.x;
    int row0 = blockIdx.x * 128;
    int wv = tid >> 6, l = tid & 63, lm = l & 15, q = l >> 4;

    const unsigned short* pa0 = A + (size_t)min(row0 + wv * 32 + lm,      M - 1) * NF;
    const unsigned short* pa1 = A + (size_t)min(row0 + wv * 32 + 16 + lm, M - 1) * NF;
    const unsigned short* pwa = Wa + lm * NF;
    const unsigned short* pwb = Wb + lm * NF;

    f32x4 acc[2][8];
    #pragma unroll
    for (int i = 0; i < 2; ++i)
        #pragma unroll
        for (int j = 0; j < 8; ++j) acc[i][j] = (f32x4){0.f, 0.f, 0.f, 0.f};

    #pragma unroll
    for (int ks = 0; ks < 4; ++ks) {                // pass 1: mid = A @ Wa^T
        int ko = ks * 32 + q * 8;
        bf16x8 a0 = *(const bf16x8*)(pa0 + ko);
        bf16x8 a1 = *(const bf16x8*)(pa1 + ko);
        #pragma unroll
        for (int ct = 0; ct < 8; ++ct) {
            bf16x8 b = *(const bf16x8*)(pwa + ct * 16 * NF + ko);
            acc[0][ct] = __builtin_amdgcn_mfma_f32_16x16x32_bf16(a0, b, acc[0][ct], 0, 0, 0);
            acc[1][ct] = __builtin_amdgcn_mfma_f32_16x16x32_bf16(a1, b, acc[1][ct], 0, 0, 0);
        }
    }

    // mid -> LDS with bias+relu+bf16 (C-layout: col=lane&15, row=quad*4+reg)
    #pragma unroll
    for (int rt = 0; rt < 2; ++rt)
        #pragma unroll
        for (int ct = 0; ct < 8; ++ct) {
            int col = ct * 16 + lm;
            float bv = ba[col];
            #pragma unroll
            for (int r = 0; r < 4; ++r) {
                int rr = wv * 32 + rt * 16 + q * 4 + r;
                Mid[rr * 136 + col] = f2bf(fmaxf(acc[rt][ct][r] + bv, 0.f));
            }
        }
    __syncthreads();

    #pragma unroll
    for (int i = 0; i < 2; ++i)
        #pragma unroll
        for (int j = 0; j < 8; ++j) acc[i][j] = (f32x4){0.f, 0.f, 0.f, 0.f};

    const unsigned short* pm0 = &Mid[(wv * 32 + lm) * 136];
    const unsigned short* pm1 = &Mid[(wv * 32 + 16 + lm) * 136];
    #pragma unroll
    for (int ks = 0; ks < 4; ++ks) {                // pass 2: out = mid @ Wb^T
        int ko = ks * 32 + q * 8;
        bf16x8 a0 = *(const bf16x8*)(pm0 + ko);
        bf16x8 a1 = *(const bf16x8*)(pm1 + ko);
        #pragma unroll
        for (int ct = 0; ct < 8; ++ct) {
            bf16x8 b = *(const bf16x8*)(pwb + ct * 16 * NF + ko);
            acc[0][ct] = __builtin_amdgcn_mfma_f32_16x16x32_bf16(a0, b, acc[0][ct], 0, 0, 0);
            acc[1][ct] = __builtin_amdgcn_mfma_f32_16x16x32_bf16(a1, b, acc[1][ct], 0, 0, 0);
        }
    }

    #pragma unroll
    for (int rt = 0; rt < 2; ++rt)
        #pragma unroll
        for (int ct = 0; ct < 8; ++ct) {
            int col = ct * 16 + lm;
            float bv = bb[col];
            #pragma unroll
            for (int r = 0; r < 4; ++r) {
                int row = row0 + wv * 32 + rt * 16 + q * 4 + r;
                if (row < M) {
                    float v = fmaxf(acc[rt][ct][r] + bv, 0.f);
                    if (F32OUT) ((float*)Cout)[(size_t)row * NF + col] = v;
                    else ((unsigned short*)Cout)[(size_t)row * NF + col] = f2bf(v);
                }
            }
        }
}

// ---------------------------------------------------------------- pooling (batch sorted)
__global__ __launch_bounds__(256) void pool_sum2(const float* __restrict__ h,
                                                 const int* __restrict__ batch,
                                                 float* __restrict__ sums) {
    int t = threadIdx.x;
    int f = t & 127, seg = t >> 7;
    int n0 = blockIdx.x * 128 + seg * 64;
    if (n0 >= N_NODES) return;
    int n1 = min(n0 + 64, N_NODES);
    int cur = batch[n0];
    float acc = 0.f;
    for (int n = n0; n < n1; ++n) {
        int g = batch[n];
        if (g != cur) {
            atomicAdd(&sums[cur * NF + f], acc);
            acc = 0.f; cur = g;
        }
        acc += h[(size_t)n * NF + f];
    }
    atomicAdd(&sums[cur * NF + f], acc);
}

__global__ __launch_bounds__(256) void pool_div2(const float* __restrict__ sums,
                                                 const int* __restrict__ batch,
                                                 float* __restrict__ out) {
    int i = blockIdx.x * 256 + threadIdx.x;
    if (i >= N_GRAPHS * NF) return;
    int g = i >> 7;
    int lo = 0, hi = N_NODES;
    while (lo < hi) { int m = (lo + hi) >> 1; if (batch[m] < g) lo = m + 1; else hi = m; }
    int lo2 = lo, hi2 = N_NODES;
    while (lo2 < hi2) { int m = (lo2 + hi2) >> 1; if (batch[m] < g + 1) lo2 = m + 1; else hi2 = m; }
    float cnt = (float)(lo2 - lo);
    out[i] = sums[i] / fmaxf(cnt, 1.f);
}

// ----------------------------------------------------------------
extern "C" void kernel_launch(void* const* d_in, const int* in_sizes, int n_in,
                              void* d_out, int out_size, void* d_ws, size_t ws_size,
                              hipStream_t stream) {
    const float* x     = (const float*)d_in[0];
    const int*   ei    = (const int*)d_in[1];
    const int*   batch = (const int*)d_in[2];
    const float* W1 = (const float*)d_in[3];  const float* b1 = (const float*)d_in[4];
    const float* W2 = (const float*)d_in[5];  const float* b2 = (const float*)d_in[6];
    const float* W3 = (const float*)d_in[7];  const float* b3 = (const float*)d_in[8];
    const float* W4 = (const float*)d_in[9];  const float* b4 = (const float*)d_in[10];
    const int* src = ei;
    const int* dst = ei + N_EDGES;

    float* out   = (float*)d_out;
    float* h_out = out + N_GRAPHS * NF;            // 100000x128 fp32 (2nd output)

    // workspace (~97 MB)
    const size_t NE = (size_t)N_NODES * NF;        // 12.8M
    unsigned short* xb = (unsigned short*)d_ws;    // bf16 x
    unsigned short* t0 = xb + NE;
    unsigned short* t1 = t0 + NE;
    unsigned short* Wb = t1 + NE;                  // 4 x 128x128 bf16
    int*    rowptr = (int*)(Wb + 4 * NF * NF);     // N_NODES
    int*    rowend = rowptr + N_NODES;             // N_NODES
    int*    csr    = rowend + N_NODES;             // NBKT*CAP
    uint32* ebuf   = (uint32*)(csr + NBKT * CAP);  // NBKT*CAP
    int*    curp   = (int*)(ebuf + NBKT * CAP);    // NBKT
    float*  sums   = (float*)(curp + NBKT);        // N_GRAPHS*NF

    const int gather_blocks = N_NODES * 16 / 256;  // 6250
    const int gemm_blocks   = (N_NODES + 127) / 128; // 782

    // ---- prep: bf16 conversions + zero cursors/sums (one launch, no memsets)
    prep<<<6250 + 32 + 16, 256, 0, stream>>>((const float4*)x,
                                             (const float4*)W1, (const float4*)W2,
                                             (const float4*)W3, (const float4*)W4,
                                             (uint4*)xb, (uint4*)Wb, curp, sums);

    // ---- CSR build (fixed-capacity two-level counting sort)
    bscatter<<<EB_GRID, 256, 0, stream>>>(src, dst, curp, ebuf);
    bfine<<<NBKT, 512, 0, stream>>>(ebuf, curp, rowptr, rowend, csr);

    // ---- layer group 1: agg + fused MLP1
    gather_agg_bf16<<<gather_blocks, 256, 0, stream>>>((const uint4*)xb, rowptr, rowend, csr, (uint4*)t0);
    mlp_mfma<false><<<gemm_blocks, 256, 0, stream>>>(t0, Wb + 0 * NF * NF, b1,
                                                     Wb + 1 * NF * NF, b2, t1, N_NODES);

    // ---- layer group 2: agg + fused MLP2
    gather_agg_bf16<<<gather_blocks, 256, 0, stream>>>((const uint4*)t1, rowptr, rowend, csr, (uint4*)t0);
    mlp_mfma<true ><<<gemm_blocks, 256, 0, stream>>>(t0, Wb + 2 * NF * NF, b3,
                                                     Wb + 3 * NF * NF, b4, h_out, N_NODES);

    // ---- global mean pool
    pool_sum2<<<(N_NODES + 127) / 128, 256, 0, stream>>>(h_out, batch, sums);
    pool_div2<<<(N_GRAPHS * NF + 255) / 256, 256, 0, stream>>>(sums, batch, out);
}

// Round 7
// 409.826 us; speedup vs baseline: 1.0506x; 1.0506x over previous
//
#include <hip/hip_runtime.h>

#define N_NODES  100000
#define N_EDGES  1600000
#define NF       128
#define N_GRAPHS 100
#define NBKT     391         // ceil(100000 / 256) coarse buckets
#define BKT_SHIFT 8
#define CAP      6144        // bucket capacity; mean 4092, +32 sigma (fixed input)
#define EPB      4096        // edges per block in bscatter
#define EB_GRID  391         // ceil(1600000 / 4096)

typedef __attribute__((ext_vector_type(8))) short bf16x8;
typedef __attribute__((ext_vector_type(4))) float f32x4;
typedef unsigned int uint32;

// ---------------------------------------------------------------- bf16 helpers (RNE)
__device__ __forceinline__ unsigned short f2bf(float f) {
    union { float f; uint32 u; } x; x.f = f;
    return (unsigned short)((x.u + 0x7fffu + ((x.u >> 16) & 1u)) >> 16);
}
__device__ __forceinline__ uint32 pack2bf(float a, float b) {
    union { float f; uint32 u; } x, y; x.f = a; y.f = b;
    uint32 lo = (x.u + 0x7fffu + ((x.u >> 16) & 1u)) >> 16;
    uint32 hi = (y.u + 0x7fffu + ((y.u >> 16) & 1u)) & 0xffff0000u;
    return lo | hi;
}
__device__ __forceinline__ void add_bf8(float* acc, uint4 v) {
    uint32 u[4] = {v.x, v.y, v.z, v.w};
    #pragma unroll
    for (int i = 0; i < 4; ++i) {
        union { uint32 b; float f; } lo, hi;
        lo.b = u[i] << 16; hi.b = u[i] & 0xffff0000u;
        acc[2 * i] += lo.f; acc[2 * i + 1] += hi.f;
    }
}

// ---------------------------------------------------------------- prep: x->bf16, W1..4->bf16, zero cursors+sums
__global__ __launch_bounds__(256) void prep(const float4* __restrict__ x,
                                            const float4* __restrict__ w1,
                                            const float4* __restrict__ w2,
                                            const float4* __restrict__ w3,
                                            const float4* __restrict__ w4,
                                            uint4* __restrict__ xb, uint4* __restrict__ wb,
                                            int* __restrict__ cur, float* __restrict__ sums) {
    int bid = blockIdx.x, t = threadIdx.x;
    if (bid < 6250) {                               // x: 1.6M uint4 outputs exactly
        int i = bid * 256 + t;
        float4 a = x[i * 2], b = x[i * 2 + 1];
        uint4 o;
        o.x = pack2bf(a.x, a.y); o.y = pack2bf(a.z, a.w);
        o.z = pack2bf(b.x, b.y); o.w = pack2bf(b.z, b.w);
        xb[i] = o;
    } else if (bid < 6282) {                        // weights: 8192 uint4
        int i = (bid - 6250) * 256 + t;
        int wi = i >> 11, li = i & 2047;
        const float4* s = (wi == 0) ? w1 : (wi == 1) ? w2 : (wi == 2) ? w3 : w4;
        float4 a = s[li * 2], b = s[li * 2 + 1];
        uint4 o;
        o.x = pack2bf(a.x, a.y); o.y = pack2bf(a.z, a.w);
        o.z = pack2bf(b.x, b.y); o.w = pack2bf(b.z, b.w);
        wb[i] = o;
    } else {                                        // zero cur[391] + sums[12800]
        int idx = (bid - 6282) * 256 + t;           // 16 blocks -> 4096 threads
        for (int i = idx; i < N_GRAPHS * NF; i += 4096) sums[i] = 0.f;
        if (idx < NBKT) cur[idx] = 0;
    }
}

// ---------------------------------------------------------------- CSR A: scatter edges into fixed-cap coarse buckets
// packed entry: (dstLocal<<17) | src   (src < 131072, dstLocal < 256)
__global__ __launch_bounds__(512) void bscatter(const int* __restrict__ src,
                                                const int* __restrict__ dst,
                                                int* __restrict__ cur,
                                                uint32* __restrict__ ebuf) {
    __shared__ int lh[NBKT], lbase[NBKT];
    int t = threadIdx.x;
    if (t < NBKT) lh[t] = 0;
    __syncthreads();
    int e0 = blockIdx.x * EPB;
    int d[8];
    #pragma unroll
    for (int i = 0; i < 8; ++i) {
        int e = e0 + i * 512 + t;
        d[i] = -1;
        if (e < N_EDGES) { d[i] = dst[e]; atomicAdd(&lh[d[i] >> BKT_SHIFT], 1); }
    }
    __syncthreads();
    if (t < NBKT) { lbase[t] = t * CAP + atomicAdd(&cur[t], lh[t]); lh[t] = 0; }
    __syncthreads();
    #pragma unroll
    for (int i = 0; i < 8; ++i) {
        int e = e0 + i * 512 + t;
        if (e < N_EDGES) {
            int b = d[i] >> BKT_SHIFT;
            int off = atomicAdd(&lh[b], 1);
            ebuf[lbase[b] + off] = ((uint32)(d[i] & 255) << 17) | (uint32)src[e];
        }
    }
}

// ---------------------------------------------------------------- CSR B: per-bucket fine counting sort (256 nodes)
__global__ __launch_bounds__(256) void bfine(const uint32* __restrict__ ebuf,
                                             const int* __restrict__ cur,
                                             int* __restrict__ rowptr,
                                             int* __restrict__ rowend,
                                             int* __restrict__ csr) {
    __shared__ int deg[256], off[256];
    int t = threadIdx.x;
    int bkt = blockIdx.x;
    int beg = bkt * CAP;
    int end = beg + cur[bkt];
    deg[t] = 0;
    __syncthreads();
    for (int e = beg + t; e < end; e += 256)
        atomicAdd(&deg[ebuf[e] >> 17], 1);
    __syncthreads();
    int d = deg[t];
    off[t] = d;
    __syncthreads();
    for (int o = 1; o < 256; o <<= 1) {             // Hillis-Steele inclusive
        int x = (t >= o) ? off[t - o] : 0;
        __syncthreads();
        off[t] += x;
        __syncthreads();
    }
    int ex = off[t] - d;                            // exclusive
    int node = (bkt << BKT_SHIFT) + t;
    if (node < N_NODES) { rowptr[node] = beg + ex; rowend[node] = beg + ex + d; }
    __syncthreads();
    off[t] = ex;                                    // becomes write cursor
    __syncthreads();
    for (int e = beg + t; e < end; e += 256) {
        uint32 u = ebuf[e];
        int pos = atomicAdd(&off[u >> 17], 1);
        csr[beg + pos] = (int)(u & 0x1FFFFu);
    }
}

// ---------------------------------------------------------------- bf16 gather v2: one WAVE per node
// 64 lanes = 4 edge slots (j) x 16 feature chunks (c). Each iteration covers 16
// edges with two waitcnt rounds (16 csr loads, then 16 x-loads) instead of 16
// serial dependent round-trips. Uniform trip count ceil(deg/16) per wave (no
// degree divergence). Tail slots clamp to end-1 (dup line, L1-hit) and mask the add.
__global__ __launch_bounds__(256) void gather_agg_bf16(const uint4* __restrict__ x,
                                                       const int* __restrict__ rowptr,
                                                       const int* __restrict__ rowend,
                                                       const int* __restrict__ csr,
                                                       uint4* __restrict__ out) {
    int gid  = blockIdx.x * 256 + threadIdx.x;
    int node = gid >> 6;
    int l = threadIdx.x & 63;
    int c = l & 15;              // feature chunk (16B)
    int j = l >> 4;              // edge slot 0..3
    int beg = rowptr[node], end = rowend[node];

    float acc[8];
    #pragma unroll
    for (int i = 0; i < 8; ++i) acc[i] = 0.f;

    for (int e = beg; e < end; e += 16) {
        int s[4];
        #pragma unroll
        for (int k = 0; k < 4; ++k) {
            int ee = min(e + j + 4 * k, end - 1);
            s[k] = csr[ee];                         // 16-lane broadcast per slot
        }
        uint4 v[4];
        #pragma unroll
        for (int k = 0; k < 4; ++k) v[k] = x[s[k] * 16 + c];
        #pragma unroll
        for (int k = 0; k < 4; ++k)
            if (e + j + 4 * k < end) add_bf8(acc, v[k]);
    }

    // reduce the 4 edge-slot partials: lanes l, l^16, l^32, l^48 share chunk c
    #pragma unroll
    for (int i = 0; i < 8; ++i) {
        acc[i] += __shfl_xor(acc[i], 16, 64);
        acc[i] += __shfl_xor(acc[i], 32, 64);
    }

    add_bf8(acc, x[node * 16 + c]);                 // self term

    if (j == 0) {
        uint4 o;
        o.x = pack2bf(acc[0], acc[1]); o.y = pack2bf(acc[2], acc[3]);
        o.z = pack2bf(acc[4], acc[5]); o.w = pack2bf(acc[6], acc[7]);
        out[node * 16 + c] = o;                     // 16 lanes x 16B contiguous
    }
}

// ---------------------------------------------------------------- fused MLP: C = relu(relu(A Wa^T + ba) Wb^T + bb)
// A/W fragments straight from global (wave reads 16 rows x 64B contiguous = full
// lines; W is 32KB L1-resident). Only mid lives in LDS (35KB -> 4 blocks/CU).
template <bool F32OUT>
__global__ __launch_bounds__(256, 4) void mlp_mfma(const unsigned short* __restrict__ A,
                                                   const unsigned short* __restrict__ Wa,
                                                   const float* __restrict__ ba,
                                                   const unsigned short* __restrict__ Wb,
                                                   const float* __restrict__ bb,
                                                   void* __restrict__ Cout, int M) {
    __shared__ unsigned short Mid[128 * 136];
    int tid  = threadIdx.x;
    int row0 = blockIdx.x * 128;
    int wv = tid >> 6, l = tid & 63, lm = l & 15, q = l >> 4;

    const unsigned short* pa0 = A + (size_t)min(row0 + wv * 32 + lm,      M - 1) * NF;
    const unsigned short* pa1 = A + (size_t)min(row0 + wv * 32 + 16 + lm, M - 1) * NF;
    const unsigned short* pwa = Wa + lm * NF;
    const unsigned short* pwb = Wb + lm * NF;

    f32x4 acc[2][8];
    #pragma unroll
    for (int i = 0; i < 2; ++i)
        #pragma unroll
        for (int j = 0; j < 8; ++j) acc[i][j] = (f32x4){0.f, 0.f, 0.f, 0.f};

    #pragma unroll
    for (int ks = 0; ks < 4; ++ks) {                // pass 1: mid = A @ Wa^T
        int ko = ks * 32 + q * 8;
        bf16x8 a0 = *(const bf16x8*)(pa0 + ko);
        bf16x8 a1 = *(const bf16x8*)(pa1 + ko);
        #pragma unroll
        for (int ct = 0; ct < 8; ++ct) {
            bf16x8 b = *(const bf16x8*)(pwa + ct * 16 * NF + ko);
            acc[0][ct] = __builtin_amdgcn_mfma_f32_16x16x32_bf16(a0, b, acc[0][ct], 0, 0, 0);
            acc[1][ct] = __builtin_amdgcn_mfma_f32_16x16x32_bf16(a1, b, acc[1][ct], 0, 0, 0);
        }
    }

    #pragma unroll
    for (int rt = 0; rt < 2; ++rt)                  // mid -> LDS (bias+relu+bf16)
        #pragma unroll
        for (int ct = 0; ct < 8; ++ct) {
            int col = ct * 16 + lm;
            float bv = ba[col];
            #pragma unroll
            for (int r = 0; r < 4; ++r) {
                int rr = wv * 32 + rt * 16 + q * 4 + r;
                Mid[rr * 136 + col] = f2bf(fmaxf(acc[rt][ct][r] + bv, 0.f));
            }
        }
    __syncthreads();

    #pragma unroll
    for (int i = 0; i < 2; ++i)
        #pragma unroll
        for (int j = 0; j < 8; ++j) acc[i][j] = (f32x4){0.f, 0.f, 0.f, 0.f};

    const unsigned short* pm0 = &Mid[(wv * 32 + lm) * 136];
    const unsigned short* pm1 = &Mid[(wv * 32 + 16 + lm) * 136];
    #pragma unroll
    for (int ks = 0; ks < 4; ++ks) {                // pass 2: out = mid @ Wb^T
        int ko = ks * 32 + q * 8;
        bf16x8 a0 = *(const bf16x8*)(pm0 + ko);
        bf16x8 a1 = *(const bf16x8*)(pm1 + ko);
        #pragma unroll
        for (int ct = 0; ct < 8; ++ct) {
            bf16x8 b = *(const bf16x8*)(pwb + ct * 16 * NF + ko);
            acc[0][ct] = __builtin_amdgcn_mfma_f32_16x16x32_bf16(a0, b, acc[0][ct], 0, 0, 0);
            acc[1][ct] = __builtin_amdgcn_mfma_f32_16x16x32_bf16(a1, b, acc[1][ct], 0, 0, 0);
        }
    }

    #pragma unroll
    for (int rt = 0; rt < 2; ++rt)
        #pragma unroll
        for (int ct = 0; ct < 8; ++ct) {
            int col = ct * 16 + lm;
            float bv = bb[col];
            #pragma unroll
            for (int r = 0; r < 4; ++r) {
                int row = row0 + wv * 32 + rt * 16 + q * 4 + r;
                if (row < M) {
                    float v = fmaxf(acc[rt][ct][r] + bv, 0.f);
                    if (F32OUT) ((float*)Cout)[(size_t)row * NF + col] = v;
                    else ((unsigned short*)Cout)[(size_t)row * NF + col] = f2bf(v);
                }
            }
        }
}

// ---------------------------------------------------------------- pooling (batch sorted)
__global__ __launch_bounds__(256) void pool_sum2(const float* __restrict__ h,
                                                 const int* __restrict__ batch,
                                                 float* __restrict__ sums) {
    int t = threadIdx.x;
    int f = t & 127, seg = t >> 7;
    int n0 = blockIdx.x * 128 + seg * 64;
    if (n0 >= N_NODES) return;
    int n1 = min(n0 + 64, N_NODES);
    int cur = batch[n0];
    float acc = 0.f;
    for (int n = n0; n < n1; ++n) {
        int g = batch[n];
        if (g != cur) {
            atomicAdd(&sums[cur * NF + f], acc);
            acc = 0.f; cur = g;
        }
        acc += h[(size_t)n * NF + f];
    }
    atomicAdd(&sums[cur * NF + f], acc);
}

__global__ __launch_bounds__(256) void pool_div2(const float* __restrict__ sums,
                                                 const int* __restrict__ batch,
                                                 float* __restrict__ out) {
    int i = blockIdx.x * 256 + threadIdx.x;
    if (i >= N_GRAPHS * NF) return;
    int g = i >> 7;
    int lo = 0, hi = N_NODES;
    while (lo < hi) { int m = (lo + hi) >> 1; if (batch[m] < g) lo = m + 1; else hi = m; }
    int lo2 = lo, hi2 = N_NODES;
    while (lo2 < hi2) { int m = (lo2 + hi2) >> 1; if (batch[m] < g + 1) lo2 = m + 1; else hi2 = m; }
    float cnt = (float)(lo2 - lo);
    out[i] = sums[i] / fmaxf(cnt, 1.f);
}

// ----------------------------------------------------------------
extern "C" void kernel_launch(void* const* d_in, const int* in_sizes, int n_in,
                              void* d_out, int out_size, void* d_ws, size_t ws_size,
                              hipStream_t stream) {
    const float* x     = (const float*)d_in[0];
    const int*   ei    = (const int*)d_in[1];
    const int*   batch = (const int*)d_in[2];
    const float* W1 = (const float*)d_in[3];  const float* b1 = (const float*)d_in[4];
    const float* W2 = (const float*)d_in[5];  const float* b2 = (const float*)d_in[6];
    const float* W3 = (const float*)d_in[7];  const float* b3 = (const float*)d_in[8];
    const float* W4 = (const float*)d_in[9];  const float* b4 = (const float*)d_in[10];
    const int* src = ei;
    const int* dst = ei + N_EDGES;

    float* out   = (float*)d_out;
    float* h_out = out + N_GRAPHS * NF;            // 100000x128 fp32 (2nd output)

    // workspace (~97 MB)
    const size_t NE = (size_t)N_NODES * NF;        // 12.8M
    unsigned short* xb = (unsigned short*)d_ws;    // bf16 x
    unsigned short* t0 = xb + NE;
    unsigned short* t1 = t0 + NE;
    unsigned short* Wb = t1 + NE;                  // 4 x 128x128 bf16
    int*    rowptr = (int*)(Wb + 4 * NF * NF);     // N_NODES
    int*    rowend = rowptr + N_NODES;             // N_NODES
    int*    csr    = rowend + N_NODES;             // NBKT*CAP (~9.6MB)
    uint32* ebuf   = (uint32*)(csr + NBKT * CAP);  // NBKT*CAP
    int*    curp   = (int*)(ebuf + NBKT * CAP);    // NBKT
    float*  sums   = (float*)(curp + NBKT);        // N_GRAPHS*NF

    const int gather_blocks = N_NODES * 64 / 256;  // 25000 (one wave per node)
    const int gemm_blocks   = (N_NODES + 127) / 128; // 782

    // ---- prep: bf16 conversions + zero cursors/sums (one launch, no memsets)
    prep<<<6250 + 32 + 16, 256, 0, stream>>>((const float4*)x,
                                             (const float4*)W1, (const float4*)W2,
                                             (const float4*)W3, (const float4*)W4,
                                             (uint4*)xb, (uint4*)Wb, curp, sums);

    // ---- CSR build (fixed-capacity two-level counting sort, 256-node buckets)
    bscatter<<<EB_GRID, 512, 0, stream>>>(src, dst, curp, ebuf);
    bfine<<<NBKT, 256, 0, stream>>>(ebuf, curp, rowptr, rowend, csr);

    // ---- layer group 1: agg + fused MLP1
    gather_agg_bf16<<<gather_blocks, 256, 0, stream>>>((const uint4*)xb, rowptr, rowend, csr, (uint4*)t0);
    mlp_mfma<false><<<gemm_blocks, 256, 0, stream>>>(t0, Wb + 0 * NF * NF, b1,
                                                     Wb + 1 * NF * NF, b2, t1, N_NODES);

    // ---- layer group 2: agg + fused MLP2
    gather_agg_bf16<<<gather_blocks, 256, 0, stream>>>((const uint4*)t1, rowptr, rowend, csr, (uint4*)t0);
    mlp_mfma<true ><<<gemm_blocks, 256, 0, stream>>>(t0, Wb + 2 * NF * NF, b3,
                                                     Wb + 3 * NF * NF, b4, h_out, N_NODES);

    // ---- global mean pool
    pool_sum2<<<(N_NODES + 127) / 128, 256, 0, stream>>>(h_out, batch, sums);
    pool_div2<<<(N_GRAPHS * NF + 255) / 256, 256, 0, stream>>>(sums, batch, out);
}